// Round 6
// baseline (4916.046 us; speedup 1.0000x reference)
//
#include <hip/hip_runtime.h>

// ---------------------------------------------------------------------------
// VRAE LSTM: B=512, T=512, HE=HD=512, L=64.
// 64 groups x 8 rows; WG (512 thr) = 64-unit slice of TWO groups (A,B pair).
// U slice packed f16 in ws, loaded via asm global_load (resident in AGPRs).
// h exchange: gen-tagged u32 words (gen16|f16) in a double buffer via relaxed
// agent-scope atomics -- no drain, no flags; consumers spin on the tag.
// A/B phase interleave hides store-flight + load RTT under the other group's
// compute.
// ---------------------------------------------------------------------------

#define B_ 512
#define T_ 512
#define H_ 512

typedef _Float16 f16;
typedef _Float16 f16x8 __attribute__((ext_vector_type(8)));
typedef float f32x16 __attribute__((ext_vector_type(16)));
typedef unsigned long long u64;
typedef unsigned int u32;

// d_out floats: mu_dec[512*512] | sg_dec[512*512] | mu_enc[512*64] | sg_enc[512*64]
#define OFF_SG_DEC 262144
#define OFF_MU_ENC 524288
#define OFF_SG_ENC 557056

__device__ __forceinline__ float sigm_(float x) { return 1.f / (1.f + __expf(-x)); }
__device__ __forceinline__ float tanh_(float x) {
  float t = fabsf(x);
  float e = __expf(2.f * t);
  float r = 1.f - 2.f / (e + 1.f);
  return x < 0.f ? -r : r;
}
__device__ __forceinline__ float softplus_(float x) {
  return fmaxf(x, 0.f) + log1pf(__expf(-fabsf(x)));
}
__device__ __forceinline__ int fresh_(u64 w, u32 g) {
  return ((u32)(w >> 48) == g) & (((u32)(w >> 16) & 0xffffu) == g);
}
__device__ __forceinline__ u32 packh_(u64 w) {
  return (u32)(w & 0xffffu) | (((u32)(w >> 32) & 0xffffu) << 16);
}

// ---------------------------------------------------------------------------
// Pack U [512][2048] f32 -> f16 fragment order (unchanged from round 5):
// Upk[(((wg*8+w)*32+ks)<<9) + lane*8 + j] = U[ks*16+(lane>>5)*8+j][gcol],
//   gcol = (lane&3... ) see decomposition below.
// ---------------------------------------------------------------------------
__global__ void pack_U(const float* __restrict__ U, f16* __restrict__ Upk) {
  const int e = blockIdx.x * 256 + threadIdx.x;  // 2^20 elements
  const int j = e & 7, lane = (e >> 3) & 63, ks = (e >> 9) & 31;
  const int w = (e >> 14) & 7, wg = (e >> 17) & 7;
  const int ccol = lane & 31, khalf = lane >> 5;
  const int uu = ccol >> 2, gate = ccol & 3;
  const int k = ks * 16 + khalf * 8 + j;
  const int gcol = gate * 512 + wg * 64 + w * 8 + uu;
  Upk[e] = (f16)U[k * 2048 + gcol];
}

// ---------------------------------------------------------------------------
// IS_DEC=0: xin=[B][T] input, wa=enc_W, wb=enc_b
// IS_DEC=1: xin=zin [B][2048] (bias folded), wa=dmu_W, wb=dstd_W
// hbuf: u32 [2][512][512] gen-tagged h.
// ---------------------------------------------------------------------------
template <int IS_DEC>
__global__ void __launch_bounds__(512, 1)
lstm_rec(const f16* __restrict__ Upk,
         const float* __restrict__ xin,
         const float* __restrict__ wa,
         const float* __restrict__ wb,
         u32* __restrict__ hbuf,
         float* __restrict__ accmu,
         float* __restrict__ accsg) {
  const int bid = blockIdx.x;
  const int s = bid >> 3;
  const int j = (bid & 7) * 4 + (s & 3);  // pair 0..31 (XCD-local-ish)
  const int wg = s >> 2;                  // unit slice 0..7
  const int tid = threadIdx.x, wave = tid >> 6, lane = tid & 63;
  const int U0 = wg * 64;
  const int RA = j * 16, RB = j * 16 + 8;
  const u32 GB = IS_DEC ? 0x8000u : 0u;
  const int ccol = lane & 31, khalf = lane >> 5;

  // ---- Breg from packed U (asm volatile: cannot be rematerialized) --------
  f16x8 Breg[32];
#pragma unroll
  for (int ks = 0; ks < 32; ++ks) {
    const f16* p = Upk + (((wg * 8 + wave) * 32 + ks) << 9) + lane * 8;
    asm volatile("global_load_dwordx4 %0, %1, off\n\ts_waitcnt vmcnt(0)"
                 : "=v"(Breg[ks]) : "v"(p));
  }

  // ---- elementwise maps: thread = (row erow, unit eu) of each group -------
  const int erow = tid >> 6, eu = tid & 63;
  float xwv[4], bias[4], addA[4], addB[4];
  float dmu_w = 0.f, dstd_w = 0.f;
#pragma unroll
  for (int gt = 0; gt < 4; ++gt) {
    const int col = gt * 512 + U0 + eu;
    if (IS_DEC) {
      addA[gt] = xin[(RA + erow) * 2048 + col];
      addB[gt] = xin[(RB + erow) * 2048 + col];
      xwv[gt] = 0.f; bias[gt] = 0.f;
    } else {
      bias[gt] = wb[col];
      xwv[gt] = wa[col];
      addA[gt] = 0.f; addB[gt] = 0.f;
    }
  }
  if (IS_DEC) { dmu_w = wa[U0 + eu]; dstd_w = wb[U0 + eu]; }

  float cA = 0.f, cB = 0.f;

  __shared__ __align__(16) f16 bufA[8 * 520];
  __shared__ __align__(16) f16 bufB[8 * 520];
  __shared__ __align__(16) float gatesL[8 * 264];

  // staging indices: 4 u64 words per group per thread ([8][256] u64 tile)
  int lrow[4], lcol[4], gidxA[4], gidxB[4];
#pragma unroll
  for (int i = 0; i < 4; ++i) {
    const int w = tid + i * 512;
    lrow[i] = w >> 8; lcol[i] = w & 255;
    gidxA[i] = (RA + lrow[i]) * 256 + lcol[i];
    gidxB[i] = (RB + lrow[i]) * 256 + lcol[i];
  }
  const u64* hb64 = (const u64*)hbuf;

  // prologue: prefetch A(0) from buf0 (memset zeros = gen 0, h = 0)
  u64 wAr[4], wBr[4];
#pragma unroll
  for (int i = 0; i < 4; ++i)
    wAr[i] = __hip_atomic_load(hb64 + gidxA[i], __ATOMIC_RELAXED,
                               __HIP_MEMORY_SCOPE_AGENT);
  asm volatile("" ::: "memory");

  for (int t = 0; t < T_; ++t) {
    const int b0 = (t & 1) * 131072;         // u64 offset, read buffer
    const int b1 = ((t + 1) & 1) * 131072;   // u64 offset, write buffer
    const int c1 = ((t + 1) & 1) * 262144;   // u32 offset, write buffer
    const u32 gr = GB + (u32)t, gn = GB + (u32)t + 1u;

    // ================= A phase =================
    while (!(fresh_(wAr[0], gr) & fresh_(wAr[1], gr) &
             fresh_(wAr[2], gr) & fresh_(wAr[3], gr))) {
#pragma unroll
      for (int i = 0; i < 4; ++i)
        wAr[i] = __hip_atomic_load(hb64 + b0 + gidxA[i], __ATOMIC_RELAXED,
                                   __HIP_MEMORY_SCOPE_AGENT);
    }
#pragma unroll
    for (int i = 0; i < 4; ++i)
      *(u32*)&bufA[lrow[i] * 520 + lcol[i] * 2] = packh_(wAr[i]);
    __syncthreads();  // BAR1

    // issue B(t) prefetch (producer stored ~1 phase ago)
#pragma unroll
    for (int i = 0; i < 4; ++i)
      wBr[i] = __hip_atomic_load(hb64 + b0 + gidxB[i], __ATOMIC_RELAXED,
                                 __HIP_MEMORY_SCOPE_AGENT);
    asm volatile("" ::: "memory");

    {
      f32x16 acc;
#pragma unroll
      for (int q = 0; q < 16; ++q) acc[q] = 0.f;
#pragma unroll
      for (int ks = 0; ks < 32; ++ks) {
        f16x8 a = *(const f16x8*)&bufA[(lane & 7) * 520 + ks * 16 + khalf * 8];
        acc = __builtin_amdgcn_mfma_f32_32x32x16_f16(a, Breg[ks], acc, 0, 0, 0);
      }
#pragma unroll
      for (int r = 0; r < 4; ++r)
        gatesL[(r + 4 * khalf) * 264 + wave * 32 + ccol] = acc[r];
    }
    __syncthreads();  // BAR2

    {  // ---- ew A ----
      const float4 g4 = *(const float4*)&gatesL[erow * 264 + (eu >> 3) * 32 + (eu & 7) * 4];
      float ga0, ga1, ga2, ga3;
      if (IS_DEC) {
        ga0 = g4.x + addA[0]; ga1 = g4.y + addA[1];
        ga2 = g4.z + addA[2]; ga3 = g4.w + addA[3];
      } else {
        const float xv = xin[(RA + erow) * T_ + t];
        ga0 = g4.x + bias[0] + xv * xwv[0];
        ga1 = g4.y + bias[1] + xv * xwv[1];
        ga2 = g4.z + bias[2] + xv * xwv[2];
        ga3 = g4.w + bias[3] + xv * xwv[3];
      }
      const float cn = sigm_(ga1) * cA + sigm_(ga0) * tanh_(ga2);
      cA = cn;
      const float hn = sigm_(ga3) * tanh_(cn);
      union { f16 h; unsigned short u; } hc; hc.h = (f16)hn;
      __hip_atomic_store(hbuf + c1 + (RA + erow) * 512 + U0 + eu,
                         (gn << 16) | (u32)hc.u, __ATOMIC_RELAXED,
                         __HIP_MEMORY_SCOPE_AGENT);
      if (IS_DEC) {
        float smu = hn * dmu_w, ssg = hn * dstd_w;
#pragma unroll
        for (int o = 32; o; o >>= 1) {
          smu += __shfl_xor(smu, o);
          ssg += __shfl_xor(ssg, o);
        }
        if (lane == 0) {
          unsafeAtomicAdd(&accmu[(RA + erow) * T_ + t], smu);
          unsafeAtomicAdd(&accsg[(RA + erow) * T_ + t], ssg);
        }
      }
    }

    // ================= B phase =================
    while (!(fresh_(wBr[0], gr) & fresh_(wBr[1], gr) &
             fresh_(wBr[2], gr) & fresh_(wBr[3], gr))) {
#pragma unroll
      for (int i = 0; i < 4; ++i)
        wBr[i] = __hip_atomic_load(hb64 + b0 + gidxB[i], __ATOMIC_RELAXED,
                                   __HIP_MEMORY_SCOPE_AGENT);
    }
#pragma unroll
    for (int i = 0; i < 4; ++i)
      *(u32*)&bufB[lrow[i] * 520 + lcol[i] * 2] = packh_(wBr[i]);
    __syncthreads();  // BAR3

    // issue A(t+1) prefetch (A stored t+1 earlier this iteration)
#pragma unroll
    for (int i = 0; i < 4; ++i)
      wAr[i] = __hip_atomic_load(hb64 + b1 + gidxA[i], __ATOMIC_RELAXED,
                                 __HIP_MEMORY_SCOPE_AGENT);
    asm volatile("" ::: "memory");

    {
      f32x16 acc;
#pragma unroll
      for (int q = 0; q < 16; ++q) acc[q] = 0.f;
#pragma unroll
      for (int ks = 0; ks < 32; ++ks) {
        f16x8 a = *(const f16x8*)&bufB[(lane & 7) * 520 + ks * 16 + khalf * 8];
        acc = __builtin_amdgcn_mfma_f32_32x32x16_f16(a, Breg[ks], acc, 0, 0, 0);
      }
#pragma unroll
      for (int r = 0; r < 4; ++r)
        gatesL[(r + 4 * khalf) * 264 + wave * 32 + ccol] = acc[r];
    }
    __syncthreads();  // BAR4

    {  // ---- ew B ----
      const float4 g4 = *(const float4*)&gatesL[erow * 264 + (eu >> 3) * 32 + (eu & 7) * 4];
      float ga0, ga1, ga2, ga3;
      if (IS_DEC) {
        ga0 = g4.x + addB[0]; ga1 = g4.y + addB[1];
        ga2 = g4.z + addB[2]; ga3 = g4.w + addB[3];
      } else {
        const float xv = xin[(RB + erow) * T_ + t];
        ga0 = g4.x + bias[0] + xv * xwv[0];
        ga1 = g4.y + bias[1] + xv * xwv[1];
        ga2 = g4.z + bias[2] + xv * xwv[2];
        ga3 = g4.w + bias[3] + xv * xwv[3];
      }
      const float cn = sigm_(ga1) * cB + sigm_(ga0) * tanh_(ga2);
      cB = cn;
      const float hn = sigm_(ga3) * tanh_(cn);
      union { f16 h; unsigned short u; } hc; hc.h = (f16)hn;
      __hip_atomic_store(hbuf + c1 + (RB + erow) * 512 + U0 + eu,
                         (gn << 16) | (u32)hc.u, __ATOMIC_RELAXED,
                         __HIP_MEMORY_SCOPE_AGENT);
      if (IS_DEC) {
        float smu = hn * dmu_w, ssg = hn * dstd_w;
#pragma unroll
        for (int o = 32; o; o >>= 1) {
          smu += __shfl_xor(smu, o);
          ssg += __shfl_xor(ssg, o);
        }
        if (lane == 0) {
          unsafeAtomicAdd(&accmu[(RB + erow) * T_ + t], smu);
          unsafeAtomicAdd(&accsg[(RB + erow) * T_ + t], ssg);
        }
      }
    }
  }
}

// ---------------------------------------------------------------------------
// Encoder heads: read final h (gen-tagged u32, buf0), write mu/sg_enc + z.
// ---------------------------------------------------------------------------
__global__ void enc_heads(const u32* __restrict__ h0, const float* __restrict__ emuW,
                          const float* __restrict__ emub, const float* __restrict__ estdW,
                          const float* __restrict__ estdb, float* __restrict__ out,
                          float* __restrict__ z) {
  const int b = blockIdx.x, tid = threadIdx.x;
  __shared__ float hrow[512];
  for (int k = tid; k < 512; k += 128) {
    union { unsigned short u; f16 h; } c;
    c.u = (unsigned short)(h0[b * 512 + k] & 0xffffu);
    hrow[k] = (float)c.h;
  }
  __syncthreads();
  const int head = tid >> 6, l = tid & 63;
  const float* W = head ? estdW : emuW;
  float a = 0.f;
#pragma unroll 8
  for (int k = 0; k < 512; ++k) a += hrow[k] * W[k * 64 + l];
  if (head == 0) {
    const float v = a + emub[l];
    out[OFF_MU_ENC + b * 64 + l] = v;
    z[b * 64 + l] = v;
  } else {
    out[OFF_SG_ENC + b * 64 + l] = softplus_(a + estdb[l]);
  }
}

// ---------------------------------------------------------------------------
// Decoder prep: hd = tanh(z@dfs_W+dfs_b) -> hbuf buf0 (gen 0x8000);
//               zin = z@dec_W+dec_b
// ---------------------------------------------------------------------------
__global__ void dec_prep(const float* __restrict__ z, const float* __restrict__ dfsW,
                         const float* __restrict__ dfsb, const float* __restrict__ decW,
                         const float* __restrict__ decb, u32* __restrict__ hbuf,
                         float* __restrict__ zin) {
  const int b = blockIdx.x, tid = threadIdx.x;
  __shared__ float zl[64];
  if (tid < 64) zl[tid] = z[b * 64 + tid];
  __syncthreads();
  for (int c = tid; c < 512; c += 256) {
    float a = dfsb[c];
#pragma unroll
    for (int l = 0; l < 64; ++l) a += zl[l] * dfsW[l * 512 + c];
    union { f16 h; unsigned short u; } hc; hc.h = (f16)tanh_(a);
    hbuf[b * 512 + c] = (0x8000u << 16) | (u32)hc.u;
  }
  for (int c = tid; c < 2048; c += 256) {
    float a = decb[c];
#pragma unroll
    for (int l = 0; l < 64; ++l) a += zl[l] * decW[l * 2048 + c];
    zin[b * 2048 + c] = a;
  }
}

// ---------------------------------------------------------------------------
__global__ void finalize_k(const float* __restrict__ accmu, const float* __restrict__ accsg,
                           const float* __restrict__ dmub, const float* __restrict__ dstdb,
                           float* __restrict__ out) {
  const int i = blockIdx.x * 256 + threadIdx.x;
  out[i] = accmu[i] + dmub[0];
  out[OFF_SG_DEC + i] = softplus_(accsg[i] + dstdb[0]);
}

// ---------------------------------------------------------------------------
extern "C" void kernel_launch(void* const* d_in, const int* in_sizes, int n_in,
                              void* d_out, int out_size, void* d_ws, size_t ws_size,
                              hipStream_t stream) {
  (void)in_sizes; (void)n_in; (void)out_size; (void)ws_size;
  const float* x     = (const float*)d_in[0];
  const float* encW  = (const float*)d_in[1];
  const float* encU  = (const float*)d_in[2];
  const float* encb  = (const float*)d_in[3];
  const float* emuW  = (const float*)d_in[4];
  const float* emub  = (const float*)d_in[5];
  const float* estdW = (const float*)d_in[6];
  const float* estdb = (const float*)d_in[7];
  const float* dfsW  = (const float*)d_in[8];
  const float* dfsb  = (const float*)d_in[9];
  const float* decW  = (const float*)d_in[10];
  const float* decU  = (const float*)d_in[11];
  const float* decb  = (const float*)d_in[12];
  const float* dmuW  = (const float*)d_in[13];
  const float* dmub  = (const float*)d_in[14];
  const float* dstdW = (const float*)d_in[15];
  const float* dstdb = (const float*)d_in[16];

  char* ws = (char*)d_ws;
  u32*   hbuf  = (u32*)(ws + 0);                   // 2 MB: [2][512][512] u32
  float* accmu = (float*)(ws + (2u << 20));        // 1 MB
  float* accsg = (float*)(ws + (3u << 20));        // 1 MB
  f16*   UpkE  = (f16*)(ws + (4u << 20));          // 2 MB (dead after encoder)
  float* zin   = (float*)(ws + (4u << 20));        // 4 MB (overlays UpkE)
  f16*   UpkD  = (f16*)(ws + (8u << 20));          // 2 MB
  float* z     = (float*)(ws + (10u << 20));       // 128 KB
  float* out   = (float*)d_out;

  // zero hbuf (gen tags!) + accumulators, every launch
  hipMemsetAsync(d_ws, 0, 4u << 20, stream);

  hipLaunchKernelGGL(pack_U, dim3(4096), dim3(256), 0, stream, encU, UpkE);
  hipLaunchKernelGGL(pack_U, dim3(4096), dim3(256), 0, stream, decU, UpkD);

  hipLaunchKernelGGL((lstm_rec<0>), dim3(256), dim3(512), 0, stream,
                     UpkE, x, encW, encb, hbuf, (float*)nullptr, (float*)nullptr);
  hipLaunchKernelGGL(enc_heads, dim3(512), dim3(128), 0, stream,
                     hbuf, emuW, emub, estdW, estdb, out, z);
  hipLaunchKernelGGL(dec_prep, dim3(512), dim3(256), 0, stream,
                     z, dfsW, dfsb, decW, decb, hbuf, zin);
  hipLaunchKernelGGL((lstm_rec<1>), dim3(256), dim3(512), 0, stream,
                     UpkD, zin, dmuW, dstdW, hbuf, accmu, accsg);
  hipLaunchKernelGGL(finalize_k, dim3(1024), dim3(256), 0, stream,
                     accmu, accsg, dmub, dstdb, out);
}